// Round 1
// baseline (262.417 us; speedup 1.0000x reference)
//
#include <hip/hip_runtime.h>
#include <math.h>

#define NB 128
#define NT 2048
#define ND 256
#define NE 32
#define NL 8
#define NP 168
#define SCL 0.0625f   // 1/sqrt(256)

// workspace float offsets
#define OFF_QK   0          // 8*256      qkmat[l][d] (scale folded)
#define OFF_LATQ 2048       // 8*256      latents@w_lat_q
#define OFF_WVO  4096       // 65536      w_ctx_v @ w_lat_out
#define OFF_WSO1 69632      // 65536      w_step_out @ gate_w1[256:]
#define OFF_G0   135168     // 168*256    step_base@gate_w1[:256]+b1
#define OFF_Q2S  178176     // 168*256    step_base@w_step_q * scale
#define OFF_AV   221184     // 128*8*8*256 partial weighted sums
#define OFF_DEN  2318336    // 128*8*8    partial exp sums
#define OFF_K2   2326528    // 128*8*256
#define OFF_V2   2588672    // 128*8*256

typedef __attribute__((ext_vector_type(8))) short short8b;
typedef __attribute__((ext_vector_type(4))) float f32x4;

static __device__ __forceinline__ unsigned short f2bf(float f){
  unsigned u = __float_as_uint(f);
  u += 0x7fffu + ((u >> 16) & 1u);
  return (unsigned short)(u >> 16);
}

static __device__ __forceinline__ short8b pack8(float4 lo, float4 hi){
  short8b r;
  r[0]=(short)f2bf(lo.x); r[1]=(short)f2bf(lo.y); r[2]=(short)f2bf(lo.z); r[3]=(short)f2bf(lo.w);
  r[4]=(short)f2bf(hi.x); r[5]=(short)f2bf(hi.y); r[6]=(short)f2bf(hi.z); r[7]=(short)f2bf(hi.w);
  return r;
}

// ---------------- precompute 1: Wvo, Wso1, G0/q2s, latq ----------------
__global__ __launch_bounds__(256) void pre1(const float* __restrict__ latents,
    const float* __restrict__ wlq, const float* __restrict__ wcv,
    const float* __restrict__ wlo, const float* __restrict__ wso,
    const float* __restrict__ gw1, const float* __restrict__ gb1,
    const float* __restrict__ qpos, const float* __restrict__ lemb,
    const float* __restrict__ wsq, float* __restrict__ ws)
{
  int bid = blockIdx.x, tid = threadIdx.x;
  if (bid < 256){                 // W_vo row d = bid
    const float* a = wcv + bid*ND;
    float acc = 0.f;
    for (int k=0;k<ND;k++) acc += a[k]*wlo[k*ND+tid];
    ws[OFF_WVO + bid*ND + tid] = acc;
  } else if (bid < 512){          // W_so1 row i = bid-256
    int i = bid-256;
    const float* a = wso + i*ND;
    float acc = 0.f;
    for (int k=0;k<ND;k++) acc += a[k]*gw1[(ND+k)*ND+tid];
    ws[OFF_WSO1 + i*ND + tid] = acc;
  } else if (bid < 512+NP){       // G0 / q2s row p = bid-512
    int p = bid-512;
    float ag = gb1[tid], aq = 0.f;
    for (int j=0;j<ND;j++){
      float sb = qpos[p*ND+j] + lemb[NP*ND+j];
      ag += sb*gw1[j*ND+tid];
      aq += sb*wsq[j*ND+tid];
    }
    ws[OFF_G0  + p*ND + tid] = ag;
    ws[OFF_Q2S + p*ND + tid] = aq*SCL;
  } else {                        // latq row l
    int l = bid-(512+NP);
    float acc = 0.f;
    for (int m=0;m<ND;m++) acc += latents[l*ND+m]*wlq[m*ND+tid];
    ws[OFF_LATQ + l*ND + tid] = acc;
  }
}

// ---------------- precompute 2: qkmat[l][d] = (latq @ Wck^T)*scale ----------------
__global__ __launch_bounds__(256) void pre2(const float* __restrict__ wck, float* __restrict__ ws)
{
  int d = blockIdx.x, tid = threadIdx.x;
  float wk = wck[d*ND + tid];
  float part[NL];
  #pragma unroll
  for (int l=0;l<NL;l++) part[l] = ws[OFF_LATQ + l*ND + tid]*wk;
  #pragma unroll
  for (int m=1;m<64;m<<=1){
    #pragma unroll
    for (int l=0;l<NL;l++) part[l] += __shfl_xor(part[l], m);
  }
  __shared__ float red[4][NL];
  if ((tid&63)==0){
    #pragma unroll
    for (int l=0;l<NL;l++) red[tid>>6][l] = part[l];
  }
  __syncthreads();
  if (tid < NL){
    float s = red[0][tid]+red[1][tid]+red[2][tid]+red[3][tid];
    ws[OFF_QK + tid*ND + d] = s*SCL;
  }
}

// ---------------- kernel A: flash attn1 partials (unnormalized exp) ----------------
// grid = 128*8 ; block 256.  Each block: batch b, t-range [sp*256, sp*256+256)
__global__ __launch_bounds__(256) void kA(const float* __restrict__ ctx, float* __restrict__ ws)
{
  int bid = blockIdx.x;
  int b = bid >> 3, sp = bid & 7;
  int tid = threadIdx.x;
  int wv = tid >> 6, lane = tid & 63;
  int c = lane & 15, g = lane >> 4;

  // A fragments: qkmat rows 0..7 (rows 8..15 zero-pad)
  short8b afrag[8];
  if (c < NL){
    const float* qk = ws + OFF_QK + c*ND + g*8;
    #pragma unroll
    for (int kk=0;kk<8;kk++){
      float4 lo = *(const float4*)(qk + kk*32);
      float4 hi = *(const float4*)(qk + kk*32 + 4);
      afrag[kk] = pack8(lo, hi);
    }
  } else {
    short8b z;
    #pragma unroll
    for (int j=0;j<8;j++) z[j] = 0;
    #pragma unroll
    for (int kk=0;kk<8;kk++) afrag[kk] = z;
  }

  __shared__ float e_lds[2][64][8];
  __shared__ float den_scr[4][8];

  float av[8];
  #pragma unroll
  for (int l=0;l<8;l++) av[l] = 0.f;
  float4 dacc = make_float4(0.f,0.f,0.f,0.f);

  const int T0 = sp*256;
  for (int sub=0; sub<4; ++sub){
    // ---- phase 1: s = qk . ctx^T via MFMA, this wave handles 16 t rows
    int tt = T0 + sub*64 + wv*16 + c;
    const float* cp = ctx + ((size_t)b*NT + tt)*ND + g*8;
    f32x4 acc = {0.f,0.f,0.f,0.f};
    #pragma unroll
    for (int kk=0;kk<8;kk++){
      float4 lo = *(const float4*)(cp + kk*32);
      float4 hi = *(const float4*)(cp + kk*32 + 4);
      short8b bfr = pack8(lo, hi);
      acc = __builtin_amdgcn_mfma_f32_16x16x32_bf16(afrag[kk], bfr, acc, 0, 0, 0);
    }
    float ex0 = __expf(acc[0]);
    float ex1 = __expf(acc[1]);
    float ex2 = __expf(acc[2]);
    float ex3 = __expf(acc[3]);
    if (g < 2){  // rows l = g*4 + i  are real
      float4 ev = make_float4(ex0,ex1,ex2,ex3);
      *(float4*)&e_lds[sub&1][wv*16 + c][g*4] = ev;
      dacc.x += ex0; dacc.y += ex1; dacc.z += ex2; dacc.w += ex3;
    }
    __syncthreads();
    // ---- phase 2: av[l][d=tid] += e[l][t]*ctx[t][d]  (ctx re-read from L2)
    const float* cp2 = ctx + ((size_t)b*NT + T0 + sub*64)*ND + tid;
    const float* eb = &e_lds[sub&1][0][0];
    #pragma unroll 4
    for (int t=0;t<64;++t){
      float cvv = cp2[t*ND];
      float4 ea  = *(const float4*)(eb + t*8);
      float4 ebv = *(const float4*)(eb + t*8 + 4);
      av[0] += ea.x*cvv;  av[1] += ea.y*cvv;  av[2] += ea.z*cvv;  av[3] += ea.w*cvv;
      av[4] += ebv.x*cvv; av[5] += ebv.y*cvv; av[6] += ebv.z*cvv; av[7] += ebv.w*cvv;
    }
  }
  // ---- den reduce: over the 16 cols of each g-group
  #pragma unroll
  for (int m=1;m<16;m<<=1){
    dacc.x += __shfl_xor(dacc.x, m);
    dacc.y += __shfl_xor(dacc.y, m);
    dacc.z += __shfl_xor(dacc.z, m);
    dacc.w += __shfl_xor(dacc.w, m);
  }
  if (g < 2 && c == 0){
    den_scr[wv][g*4+0] = dacc.x; den_scr[wv][g*4+1] = dacc.y;
    den_scr[wv][g*4+2] = dacc.z; den_scr[wv][g*4+3] = dacc.w;
  }
  __syncthreads();
  if (tid < NL){
    float s = den_scr[0][tid]+den_scr[1][tid]+den_scr[2][tid]+den_scr[3][tid];
    ws[OFF_DEN + (b*8+sp)*8 + tid] = s;
  }
  #pragma unroll
  for (int l=0;l<8;l++)
    ws[OFF_AV + ((size_t)((b*8+sp)*8 + l))*ND + tid] = av[l];
}

// ---------------- kernel B1: combine + lat_ctx + k2/v2 (per b) ----------------
__global__ __launch_bounds__(256) void kB1(const float* __restrict__ wlk,
                                           const float* __restrict__ wlv,
                                           float* __restrict__ ws)
{
  int b = blockIdx.x;
  int d = threadIdx.x;
  __shared__ float avnT[256][8];
  __shared__ float latT[256][8];

  float dent[8];
  #pragma unroll
  for (int l=0;l<8;l++){
    float s = 0.f;
    for (int sp=0;sp<8;sp++) s += ws[OFF_DEN + (b*8+sp)*8 + l];
    dent[l] = s;
  }
  float av8[8];
  #pragma unroll
  for (int l=0;l<8;l++){
    float s = 0.f;
    for (int sp=0;sp<8;sp++) s += ws[OFF_AV + ((size_t)((b*8+sp)*8 + l))*ND + d];
    av8[l] = s / dent[l];
  }
  *(float4*)&avnT[d][0] = make_float4(av8[0],av8[1],av8[2],av8[3]);
  *(float4*)&avnT[d][4] = make_float4(av8[4],av8[5],av8[6],av8[7]);
  __syncthreads();

  float lc[8];
  #pragma unroll
  for (int l=0;l<8;l++) lc[l] = 0.f;
  for (int dd=0;dd<ND;dd++){
    float w = ws[OFF_WVO + dd*ND + d];
    float4 a0 = *(const float4*)&avnT[dd][0];
    float4 a1 = *(const float4*)&avnT[dd][4];
    lc[0]+=a0.x*w; lc[1]+=a0.y*w; lc[2]+=a0.z*w; lc[3]+=a0.w*w;
    lc[4]+=a1.x*w; lc[5]+=a1.y*w; lc[6]+=a1.z*w; lc[7]+=a1.w*w;
  }
  *(float4*)&latT[d][0] = make_float4(lc[0],lc[1],lc[2],lc[3]);
  *(float4*)&latT[d][4] = make_float4(lc[4],lc[5],lc[6],lc[7]);
  __syncthreads();

  float k2a[8], v2a[8];
  #pragma unroll
  for (int l=0;l<8;l++){ k2a[l]=0.f; v2a[l]=0.f; }
  for (int dd=0;dd<ND;dd++){
    float wk = wlk[dd*ND + d];
    float wvv = wlv[dd*ND + d];
    float4 a0 = *(const float4*)&latT[dd][0];
    float4 a1 = *(const float4*)&latT[dd][4];
    k2a[0]+=a0.x*wk; k2a[1]+=a0.y*wk; k2a[2]+=a0.z*wk; k2a[3]+=a0.w*wk;
    k2a[4]+=a1.x*wk; k2a[5]+=a1.y*wk; k2a[6]+=a1.z*wk; k2a[7]+=a1.w*wk;
    v2a[0]+=a0.x*wvv; v2a[1]+=a0.y*wvv; v2a[2]+=a0.z*wvv; v2a[3]+=a0.w*wvv;
    v2a[4]+=a1.x*wvv; v2a[5]+=a1.y*wvv; v2a[6]+=a1.z*wvv; v2a[7]+=a1.w*wvv;
  }
  #pragma unroll
  for (int l=0;l<8;l++){
    ws[OFF_K2 + (b*8+l)*ND + d] = k2a[l];
    ws[OFF_V2 + (b*8+l)*ND + d] = v2a[l];
  }
}

// ---------------- kernel B2: attn2 + gate + top2 + output ----------------
// grid = 128*6 ; block 256 ; p-tile = 28
__global__ __launch_bounds__(256) void kB2(const float* __restrict__ ws,
    const float* __restrict__ gw2, const float* __restrict__ gb2,
    const float* __restrict__ qe, float* __restrict__ out)
{
  int bid = blockIdx.x;
  int b = bid / 6, p0 = (bid % 6)*28;
  int tid = threadIdx.x;

  __shared__ float q2h[28][260];     // q2s tile, later h
  __shared__ float k2s[8][260];
  __shared__ float aos[28][260];
  __shared__ float wexp[28][8];
  __shared__ float lg[28][33];
  __shared__ float4 sel[28];

  // S0: stage
  for (int i=0;i<28;i++){
    int idx = tid + i*256;
    int r = idx >> 8, cc = idx & 255;
    q2h[r][cc] = ws[OFF_Q2S + (p0+r)*ND + cc];
  }
  for (int i=0;i<8;i++){
    int idx = tid + i*256;
    int l = idx >> 8, j = idx & 255;
    k2s[l][j] = ws[OFF_K2 + (b*8+l)*ND + j];
  }
  float v2r[8];
  #pragma unroll
  for (int l=0;l<8;l++) v2r[l] = ws[OFF_V2 + (b*8+l)*ND + tid];
  __syncthreads();

  // S1: s2 dots + softmax over L=8 (no max-sub needed; logits tiny)
  {
    int pp = tid >> 3, l1 = tid & 7;
    if (pp < 28){
      float s2 = 0.f;
      #pragma unroll 8
      for (int i=0;i<64;i++){
        float4 qa = *(const float4*)&q2h[pp][4*i];
        float4 kb = *(const float4*)&k2s[l1][4*i];
        s2 += qa.x*kb.x + qa.y*kb.y + qa.z*kb.z + qa.w*kb.w;
      }
      float e2 = __expf(s2);
      float den = e2;
      den += __shfl_xor(den,1); den += __shfl_xor(den,2); den += __shfl_xor(den,4);
      wexp[pp][l1] = e2/den;
    }
  }
  __syncthreads();

  // S2: ao[p][i=tid] = sum_l w[p][l]*v2[l][i]
  for (int p=0;p<28;p++){
    float4 w0 = *(const float4*)&wexp[p][0];
    float4 w1v = *(const float4*)&wexp[p][4];
    float a = w0.x*v2r[0]+w0.y*v2r[1]+w0.z*v2r[2]+w0.w*v2r[3]
            + w1v.x*v2r[4]+w1v.y*v2r[5]+w1v.z*v2r[6]+w1v.w*v2r[7];
    aos[p][tid] = a;
  }
  __syncthreads();

  // S3: x = G0 + ao @ W_so1 ; h = gelu(x)  (register tiled 7p x 4c)
  {
    int cq = tid & 63, pg = tid >> 6;
    int c0 = cq*4;
    float xacc[7][4];
    #pragma unroll
    for (int r7=0;r7<7;r7++){
      float4 g0 = *(const float4*)&ws[OFF_G0 + (p0+pg*7+r7)*ND + c0];
      xacc[r7][0]=g0.x; xacc[r7][1]=g0.y; xacc[r7][2]=g0.z; xacc[r7][3]=g0.w;
    }
    for (int i0=0;i0<ND;i0+=4){
      float4 w0 = *(const float4*)&ws[OFF_WSO1 + (i0+0)*ND + c0];
      float4 w1 = *(const float4*)&ws[OFF_WSO1 + (i0+1)*ND + c0];
      float4 w2 = *(const float4*)&ws[OFF_WSO1 + (i0+2)*ND + c0];
      float4 w3 = *(const float4*)&ws[OFF_WSO1 + (i0+3)*ND + c0];
      #pragma unroll
      for (int r7=0;r7<7;r7++){
        float4 a4 = *(const float4*)&aos[pg*7+r7][i0];
        xacc[r7][0] += a4.x*w0.x + a4.y*w1.x + a4.z*w2.x + a4.w*w3.x;
        xacc[r7][1] += a4.x*w0.y + a4.y*w1.y + a4.z*w2.y + a4.w*w3.y;
        xacc[r7][2] += a4.x*w0.z + a4.y*w1.z + a4.z*w2.z + a4.w*w3.z;
        xacc[r7][3] += a4.x*w0.w + a4.y*w1.w + a4.z*w2.w + a4.w*w3.w;
      }
    }
    __syncthreads();   // q2h reads (S1) all done; safe to overwrite with h
    #pragma unroll
    for (int r7=0;r7<7;r7++){
      float4 h4;
      float x0=xacc[r7][0], x1=xacc[r7][1], x2=xacc[r7][2], x3=xacc[r7][3];
      h4.x = 0.5f*x0*(1.f+erff(x0*0.70710678118654752f));
      h4.y = 0.5f*x1*(1.f+erff(x1*0.70710678118654752f));
      h4.z = 0.5f*x2*(1.f+erff(x2*0.70710678118654752f));
      h4.w = 0.5f*x3*(1.f+erff(x3*0.70710678118654752f));
      *(float4*)&q2h[pg*7+r7][c0] = h4;
    }
  }
  __syncthreads();

  // S4: logits = h @ gw2 + b2   (thread = (e, 4p))
  {
    int e = tid & 31, pq = tid >> 5;
    if (pq < 7){
      float b2v = gb2[e];
      float a0=b2v, a1=b2v, a2=b2v, a3=b2v;
      for (int cc=0;cc<ND;cc+=4){
        float w20 = gw2[(cc+0)*NE + e];
        float w21 = gw2[(cc+1)*NE + e];
        float w22 = gw2[(cc+2)*NE + e];
        float w23 = gw2[(cc+3)*NE + e];
        float4 h0 = *(const float4*)&q2h[pq*4+0][cc];
        float4 h1 = *(const float4*)&q2h[pq*4+1][cc];
        float4 h2 = *(const float4*)&q2h[pq*4+2][cc];
        float4 h3 = *(const float4*)&q2h[pq*4+3][cc];
        a0 += h0.x*w20 + h0.y*w21 + h0.z*w22 + h0.w*w23;
        a1 += h1.x*w20 + h1.y*w21 + h1.z*w22 + h1.w*w23;
        a2 += h2.x*w20 + h2.y*w21 + h2.z*w22 + h2.w*w23;
        a3 += h3.x*w20 + h3.y*w21 + h3.z*w22 + h3.w*w23;
      }
      lg[pq*4+0][e] = a0;
      lg[pq*4+1][e] = a1;
      lg[pq*4+2][e] = a2;
      lg[pq*4+3][e] = a3;
    }
  }
  __syncthreads();

  // S5: top-2 + masked softmax weights
  if (tid < 28){
    float m1 = -1e30f, m2 = -1e30f;
    int e1 = 0, ee2 = 0;
    for (int e3=0;e3<NE;e3++){
      float v = lg[tid][e3];
      if (v > m1){ m2 = m1; ee2 = e1; m1 = v; e1 = e3; }
      else if (v > m2){ m2 = v; ee2 = e3; }
    }
    float z = __expf(m2 - m1);
    float inv = 1.f/(1.f+z);
    sel[tid] = make_float4(__int_as_float(e1), __int_as_float(ee2), inv, z*inv);
  }
  __syncthreads();

  // S6: output mix
  for (int p=0;p<28;p++){
    float4 s = sel[p];
    int e1 = __float_as_int(s.x), ee2 = __float_as_int(s.y);
    float q1v = qe[((size_t)e1*NP + (p0+p))*ND + tid];
    float q2v = qe[((size_t)ee2*NP + (p0+p))*ND + tid];
    out[((size_t)b*NP + (p0+p))*ND + tid] = s.z*q1v + s.w*q2v;
  }
}

extern "C" void kernel_launch(void* const* d_in, const int* in_sizes, int n_in,
                              void* d_out, int out_size, void* d_ws, size_t ws_size,
                              hipStream_t stream)
{
  const float* ctx  = (const float*)d_in[0];
  const float* qe   = (const float*)d_in[1];
  const float* qpos = (const float*)d_in[2];
  const float* lemb = (const float*)d_in[3];
  const float* lat  = (const float*)d_in[4];
  const float* wlq  = (const float*)d_in[5];
  const float* wck  = (const float*)d_in[6];
  const float* wcv  = (const float*)d_in[7];
  const float* wlo  = (const float*)d_in[8];
  const float* wsq  = (const float*)d_in[9];
  const float* wlk  = (const float*)d_in[10];
  const float* wlv  = (const float*)d_in[11];
  const float* wso  = (const float*)d_in[12];
  const float* gw1  = (const float*)d_in[13];
  const float* gb1  = (const float*)d_in[14];
  const float* gw2  = (const float*)d_in[15];
  const float* gb2  = (const float*)d_in[16];
  float* out = (float*)d_out;
  float* ws  = (float*)d_ws;

  pre1<<<512+NP+NL, 256, 0, stream>>>(lat, wlq, wcv, wlo, wso, gw1, gb1, qpos, lemb, wsq, ws);
  pre2<<<256, 256, 0, stream>>>(wck, ws);
  kA  <<<NB*8, 256, 0, stream>>>(ctx, ws);
  kB1 <<<NB, 256, 0, stream>>>(wlk, wlv, ws);
  kB2 <<<NB*6, 256, 0, stream>>>(ws, gw2, gb2, qe, out);
}

// Round 2
// 209.761 us; speedup vs baseline: 1.2510x; 1.2510x over previous
//
#include <hip/hip_runtime.h>
#include <math.h>

#define NB 128
#define NT 2048
#define ND 256
#define NE 32
#define NL 8
#define NP 168
#define SCL 0.0625f   // 1/sqrt(256)

// workspace float offsets
#define OFF_QK   0          // 8*256      qkmat[l][d] (scale folded)
#define OFF_LATQ 2048       // 8*256      latents@w_lat_q
#define OFF_WVO  4096       // 65536      w_ctx_v @ w_lat_out
#define OFF_WSO1 69632      // 65536      w_step_out @ gate_w1[256:]
#define OFF_G0   135168     // 168*256    step_base@gate_w1[:256]+b1
#define OFF_Q2S  178176     // 168*256    step_base@w_step_q * scale
#define OFF_AV   221184     // 128*8*8*256 partial weighted sums
#define OFF_DEN  2318336    // 128*8*8    partial exp sums
#define OFF_K2   2326528    // 128*8*256
#define OFF_V2   2588672    // 128*8*256

typedef __attribute__((ext_vector_type(8))) short short8b;
typedef __attribute__((ext_vector_type(4))) float f32x4;

static __device__ __forceinline__ unsigned short f2bf(float f){
  unsigned u = __float_as_uint(f);
  u += 0x7fffu + ((u >> 16) & 1u);
  return (unsigned short)(u >> 16);
}

static __device__ __forceinline__ short8b pack8(float4 lo, float4 hi){
  short8b r;
  r[0]=(short)f2bf(lo.x); r[1]=(short)f2bf(lo.y); r[2]=(short)f2bf(lo.z); r[3]=(short)f2bf(lo.w);
  r[4]=(short)f2bf(hi.x); r[5]=(short)f2bf(hi.y); r[6]=(short)f2bf(hi.z); r[7]=(short)f2bf(hi.w);
  return r;
}

// ---------------- precompute 1: Wvo, Wso1, G0/q2s, latq ----------------
__global__ __launch_bounds__(256) void pre1(const float* __restrict__ latents,
    const float* __restrict__ wlq, const float* __restrict__ wcv,
    const float* __restrict__ wlo, const float* __restrict__ wso,
    const float* __restrict__ gw1, const float* __restrict__ gb1,
    const float* __restrict__ qpos, const float* __restrict__ lemb,
    const float* __restrict__ wsq, float* __restrict__ ws)
{
  int bid = blockIdx.x, tid = threadIdx.x;
  if (bid < 256){                 // W_vo row d = bid
    const float* a = wcv + bid*ND;
    float acc = 0.f;
    #pragma unroll 8
    for (int k=0;k<ND;k++) acc += a[k]*wlo[k*ND+tid];
    ws[OFF_WVO + bid*ND + tid] = acc;
  } else if (bid < 512){          // W_so1 row i = bid-256
    int i = bid-256;
    const float* a = wso + i*ND;
    float acc = 0.f;
    #pragma unroll 8
    for (int k=0;k<ND;k++) acc += a[k]*gw1[(ND+k)*ND+tid];
    ws[OFF_WSO1 + i*ND + tid] = acc;
  } else if (bid < 512+NP){       // G0 / q2s row p = bid-512
    int p = bid-512;
    float ag = gb1[tid], aq = 0.f;
    #pragma unroll 4
    for (int j=0;j<ND;j++){
      float sb = qpos[p*ND+j] + lemb[NP*ND+j];
      ag += sb*gw1[j*ND+tid];
      aq += sb*wsq[j*ND+tid];
    }
    ws[OFF_G0  + p*ND + tid] = ag;
    ws[OFF_Q2S + p*ND + tid] = aq*SCL;
  } else {                        // latq row l
    int l = bid-(512+NP);
    float acc = 0.f;
    #pragma unroll 8
    for (int m=0;m<ND;m++) acc += latents[l*ND+m]*wlq[m*ND+tid];
    ws[OFF_LATQ + l*ND + tid] = acc;
  }
}

// ---------------- precompute 2: qkmat[l][d] = (latq @ Wck^T)*scale ----------------
__global__ __launch_bounds__(256) void pre2(const float* __restrict__ wck, float* __restrict__ ws)
{
  int d = blockIdx.x, tid = threadIdx.x;
  float wk = wck[d*ND + tid];
  float part[NL];
  #pragma unroll
  for (int l=0;l<NL;l++) part[l] = ws[OFF_LATQ + l*ND + tid]*wk;
  #pragma unroll
  for (int m=1;m<64;m<<=1){
    #pragma unroll
    for (int l=0;l<NL;l++) part[l] += __shfl_xor(part[l], m);
  }
  __shared__ float red[4][NL];
  if ((tid&63)==0){
    #pragma unroll
    for (int l=0;l<NL;l++) red[tid>>6][l] = part[l];
  }
  __syncthreads();
  if (tid < NL){
    float s = red[0][tid]+red[1][tid]+red[2][tid]+red[3][tid];
    ws[OFF_QK + tid*ND + d] = s*SCL;
  }
}

// ---------------- kernel A: flash attn1 partials, single HBM pass ----------------
// grid = 128*8 ; block 256.  Block (b,sp): rows [sp*256, sp*256+256), 4 subs of 64.
// ctx staged to LDS fp32 (XOR-swizzled 16B slots), phase 2 reads LDS only.
__global__ __launch_bounds__(256) void kA(const float* __restrict__ ctx, float* __restrict__ ws)
{
  __shared__ float ctile[64*256];   // 64KB: rows 0..63, swizzled slots
  __shared__ float efull[256*8];    // 8KB: e[t_local][l]

  int bid = blockIdx.x;
  int b = bid >> 3, sp = bid & 7;
  int tid = threadIdx.x;
  int wv = tid >> 6, lane = tid & 63;
  int c = lane & 15, g = lane >> 4;
  int dq = lane;                    // phase-2 col-quad (0..63), tq = wv

  // A fragments: qkmat rows 0..7 (rows 8..15 zero-pad)
  short8b afrag[8];
  if (c < NL){
    const float* qk = ws + OFF_QK + c*ND + g*8;
    #pragma unroll
    for (int kk=0;kk<8;kk++){
      float4 lo = *(const float4*)(qk + kk*32);
      float4 hi = *(const float4*)(qk + kk*32 + 4);
      afrag[kk] = pack8(lo, hi);
    }
  } else {
    short8b z;
    #pragma unroll
    for (int j=0;j<8;j++) z[j] = 0;
    #pragma unroll
    for (int kk=0;kk<8;kk++) afrag[kk] = z;
  }

  float av[8][4];
  #pragma unroll
  for (int l=0;l<8;l++){
    #pragma unroll
    for (int j=0;j<4;j++) av[l][j] = 0.f;
  }

  const int T0 = sp*256;
  #pragma unroll 1
  for (int sub=0; sub<4; ++sub){
    // ---- phase 1: load 64 rows from HBM, stage to LDS, QK^T MFMA, e to LDS
    int rr = wv*16 + c;             // row in sub (0..63)
    int r7 = rr & 7;
    const float* cp = ctx + ((size_t)(b*NT + T0 + sub*64 + rr))*ND + g*8;
    float4 lo[8], hi[8];
    #pragma unroll
    for (int kk=0;kk<8;kk++){
      lo[kk] = *(const float4*)(cp + kk*32);
      hi[kk] = *(const float4*)(cp + kk*32 + 4);
    }
    float* crow = ctile + rr*256;
    #pragma unroll
    for (int kk=0;kk<8;kk++){
      int slo = 2*g + 8*kk;
      *(float4*)(crow + (((slo  ) ^ r7)<<2)) = lo[kk];
      *(float4*)(crow + (((slo+1) ^ r7)<<2)) = hi[kk];
    }
    f32x4 acc = {0.f,0.f,0.f,0.f};
    #pragma unroll
    for (int kk=0;kk<8;kk++)
      acc = __builtin_amdgcn_mfma_f32_16x16x32_bf16(afrag[kk], pack8(lo[kk],hi[kk]), acc, 0, 0, 0);
    if (g < 2){   // rows l = g*4+j real
      float4 ev = make_float4(__expf(acc[0]),__expf(acc[1]),__expf(acc[2]),__expf(acc[3]));
      *(float4*)&efull[(sub*64 + rr)*8 + g*4] = ev;
    }
    __syncthreads();
    // ---- phase 2: av[l][j] += e[l][t] * ctx[t][dq*4+j], 16 rows per thread
    #pragma unroll
    for (int i=0;i<16;i++){
      int tl = wv*16 + i;
      float4 c4 = *(const float4*)(ctile + tl*256 + ((dq ^ (tl&7))<<2));
      const float* ep = efull + (sub*64 + tl)*8;
      float4 e0 = *(const float4*)ep;
      float4 e1 = *(const float4*)(ep+4);
      float e8[8];
      e8[0]=e0.x; e8[1]=e0.y; e8[2]=e0.z; e8[3]=e0.w;
      e8[4]=e1.x; e8[5]=e1.y; e8[6]=e1.z; e8[7]=e1.w;
      #pragma unroll
      for (int l=0;l<8;l++){
        av[l][0] += e8[l]*c4.x;
        av[l][1] += e8[l]*c4.y;
        av[l][2] += e8[l]*c4.z;
        av[l][3] += e8[l]*c4.w;
      }
    }
    __syncthreads();
  }

  // ---- cross-group (tq) reduce of av via LDS (alias ctile; reads done)
  float* red = ctile;  // [l][tq][dq][4] = 8*4*64*4 floats
  #pragma unroll
  for (int l=0;l<8;l++)
    *(float4*)(red + (((l*4 + wv)*64 + dq)<<2)) = make_float4(av[l][0],av[l][1],av[l][2],av[l][3]);

  // ---- den: wave 0 sums e over all 256 rows
  if (wv == 0){
    float dpart[8];
    #pragma unroll
    for (int l=0;l<8;l++) dpart[l] = 0.f;
    #pragma unroll
    for (int q=0;q<4;q++){
      const float* ep = efull + (q*64 + lane)*8;
      float4 e0 = *(const float4*)ep;
      float4 e1 = *(const float4*)(ep+4);
      dpart[0]+=e0.x; dpart[1]+=e0.y; dpart[2]+=e0.z; dpart[3]+=e0.w;
      dpart[4]+=e1.x; dpart[5]+=e1.y; dpart[6]+=e1.z; dpart[7]+=e1.w;
    }
    #pragma unroll
    for (int m=1;m<64;m<<=1){
      #pragma unroll
      for (int l=0;l<8;l++) dpart[l] += __shfl_xor(dpart[l], m);
    }
    if (lane == 0){
      #pragma unroll
      for (int l=0;l<8;l++) ws[OFF_DEN + bid*8 + l] = dpart[l];
    }
  }
  __syncthreads();

  // ---- final: sum 4 partials, write AV
  #pragma unroll
  for (int rep=0; rep<2; ++rep){
    int lidx = tid + rep*256;
    int l = lidx >> 6, d2 = lidx & 63;
    float4 s0 = *(const float4*)(red + (((l*4 + 0)*64 + d2)<<2));
    float4 s1 = *(const float4*)(red + (((l*4 + 1)*64 + d2)<<2));
    float4 s2 = *(const float4*)(red + (((l*4 + 2)*64 + d2)<<2));
    float4 s3 = *(const float4*)(red + (((l*4 + 3)*64 + d2)<<2));
    float4 o;
    o.x = s0.x+s1.x+s2.x+s3.x;
    o.y = s0.y+s1.y+s2.y+s3.y;
    o.z = s0.z+s1.z+s2.z+s3.z;
    o.w = s0.w+s1.w+s2.w+s3.w;
    *(float4*)&ws[OFF_AV + ((size_t)(bid*8 + l))*ND + d2*4] = o;
  }
}

// ---------------- kernel B1: combine + lat_ctx + k2/v2 (per b) ----------------
__global__ __launch_bounds__(256) void kB1(const float* __restrict__ wlk,
                                           const float* __restrict__ wlv,
                                           float* __restrict__ ws)
{
  int b = blockIdx.x;
  int d = threadIdx.x;
  __shared__ float avnT[256][8];
  __shared__ float latT[256][8];

  float dent[8];
  #pragma unroll
  for (int l=0;l<8;l++){
    float s = 0.f;
    for (int sp=0;sp<8;sp++) s += ws[OFF_DEN + (b*8+sp)*8 + l];
    dent[l] = s;
  }
  float av8[8];
  #pragma unroll
  for (int l=0;l<8;l++){
    float s = 0.f;
    for (int sp=0;sp<8;sp++) s += ws[OFF_AV + ((size_t)((b*8+sp)*8 + l))*ND + d];
    av8[l] = s / dent[l];
  }
  *(float4*)&avnT[d][0] = make_float4(av8[0],av8[1],av8[2],av8[3]);
  *(float4*)&avnT[d][4] = make_float4(av8[4],av8[5],av8[6],av8[7]);
  __syncthreads();

  float lc[8];
  #pragma unroll
  for (int l=0;l<8;l++) lc[l] = 0.f;
  for (int dd=0;dd<ND;dd++){
    float w = ws[OFF_WVO + dd*ND + d];
    float4 a0 = *(const float4*)&avnT[dd][0];
    float4 a1 = *(const float4*)&avnT[dd][4];
    lc[0]+=a0.x*w; lc[1]+=a0.y*w; lc[2]+=a0.z*w; lc[3]+=a0.w*w;
    lc[4]+=a1.x*w; lc[5]+=a1.y*w; lc[6]+=a1.z*w; lc[7]+=a1.w*w;
  }
  *(float4*)&latT[d][0] = make_float4(lc[0],lc[1],lc[2],lc[3]);
  *(float4*)&latT[d][4] = make_float4(lc[4],lc[5],lc[6],lc[7]);
  __syncthreads();

  float k2a[8], v2a[8];
  #pragma unroll
  for (int l=0;l<8;l++){ k2a[l]=0.f; v2a[l]=0.f; }
  for (int dd=0;dd<ND;dd++){
    float wk = wlk[dd*ND + d];
    float wvv = wlv[dd*ND + d];
    float4 a0 = *(const float4*)&latT[dd][0];
    float4 a1 = *(const float4*)&latT[dd][4];
    k2a[0]+=a0.x*wk; k2a[1]+=a0.y*wk; k2a[2]+=a0.z*wk; k2a[3]+=a0.w*wk;
    k2a[4]+=a1.x*wk; k2a[5]+=a1.y*wk; k2a[6]+=a1.z*wk; k2a[7]+=a1.w*wk;
    v2a[0]+=a0.x*wvv; v2a[1]+=a0.y*wvv; v2a[2]+=a0.z*wvv; v2a[3]+=a0.w*wvv;
    v2a[4]+=a1.x*wvv; v2a[5]+=a1.y*wvv; v2a[6]+=a1.z*wvv; v2a[7]+=a1.w*wvv;
  }
  #pragma unroll
  for (int l=0;l<8;l++){
    ws[OFF_K2 + (b*8+l)*ND + d] = k2a[l];
    ws[OFF_V2 + (b*8+l)*ND + d] = v2a[l];
  }
}

// ---------------- kernel B2: attn2 + gate + top2 + output ----------------
// grid = 128*6 ; block 256 ; p-tile = 28
__global__ __launch_bounds__(256) void kB2(const float* __restrict__ ws,
    const float* __restrict__ gw2, const float* __restrict__ gb2,
    const float* __restrict__ qe, float* __restrict__ out)
{
  int bid = blockIdx.x;
  int b = bid / 6, p0 = (bid % 6)*28;
  int tid = threadIdx.x;

  __shared__ float q2h[28][260];     // q2s tile, later h
  __shared__ float k2s[8][260];
  __shared__ float aos[28][260];
  __shared__ float wexp[28][8];
  __shared__ float lg[28][33];
  __shared__ float4 sel[28];

  // S0: stage
  for (int i=0;i<28;i++){
    int idx = tid + i*256;
    int r = idx >> 8, cc = idx & 255;
    q2h[r][cc] = ws[OFF_Q2S + (p0+r)*ND + cc];
  }
  for (int i=0;i<8;i++){
    int idx = tid + i*256;
    int l = idx >> 8, j = idx & 255;
    k2s[l][j] = ws[OFF_K2 + (b*8+l)*ND + j];
  }
  float v2r[8];
  #pragma unroll
  for (int l=0;l<8;l++) v2r[l] = ws[OFF_V2 + (b*8+l)*ND + tid];
  __syncthreads();

  // S1: s2 dots + softmax over L=8
  {
    int pp = tid >> 3, l1 = tid & 7;
    if (pp < 28){
      float s2 = 0.f;
      #pragma unroll 8
      for (int i=0;i<64;i++){
        float4 qa = *(const float4*)&q2h[pp][4*i];
        float4 kb = *(const float4*)&k2s[l1][4*i];
        s2 += qa.x*kb.x + qa.y*kb.y + qa.z*kb.z + qa.w*kb.w;
      }
      float e2 = __expf(s2);
      float den = e2;
      den += __shfl_xor(den,1); den += __shfl_xor(den,2); den += __shfl_xor(den,4);
      wexp[pp][l1] = e2/den;
    }
  }
  __syncthreads();

  // S2: ao[p][i=tid] = sum_l w[p][l]*v2[l][i]
  for (int p=0;p<28;p++){
    float4 w0 = *(const float4*)&wexp[p][0];
    float4 w1v = *(const float4*)&wexp[p][4];
    float a = w0.x*v2r[0]+w0.y*v2r[1]+w0.z*v2r[2]+w0.w*v2r[3]
            + w1v.x*v2r[4]+w1v.y*v2r[5]+w1v.z*v2r[6]+w1v.w*v2r[7];
    aos[p][tid] = a;
  }
  __syncthreads();

  // S3: x = G0 + ao @ W_so1 ; h = gelu(x)
  {
    int cq = tid & 63, pg = tid >> 6;
    int c0 = cq*4;
    float xacc[7][4];
    #pragma unroll
    for (int r7=0;r7<7;r7++){
      float4 g0 = *(const float4*)&ws[OFF_G0 + (p0+pg*7+r7)*ND + c0];
      xacc[r7][0]=g0.x; xacc[r7][1]=g0.y; xacc[r7][2]=g0.z; xacc[r7][3]=g0.w;
    }
    for (int i0=0;i0<ND;i0+=4){
      float4 w0 = *(const float4*)&ws[OFF_WSO1 + (i0+0)*ND + c0];
      float4 w1 = *(const float4*)&ws[OFF_WSO1 + (i0+1)*ND + c0];
      float4 w2 = *(const float4*)&ws[OFF_WSO1 + (i0+2)*ND + c0];
      float4 w3 = *(const float4*)&ws[OFF_WSO1 + (i0+3)*ND + c0];
      #pragma unroll
      for (int r7=0;r7<7;r7++){
        float4 a4 = *(const float4*)&aos[pg*7+r7][i0];
        xacc[r7][0] += a4.x*w0.x + a4.y*w1.x + a4.z*w2.x + a4.w*w3.x;
        xacc[r7][1] += a4.x*w0.y + a4.y*w1.y + a4.z*w2.y + a4.w*w3.y;
        xacc[r7][2] += a4.x*w0.z + a4.y*w1.z + a4.z*w2.z + a4.w*w3.z;
        xacc[r7][3] += a4.x*w0.w + a4.y*w1.w + a4.z*w2.w + a4.w*w3.w;
      }
    }
    __syncthreads();
    #pragma unroll
    for (int r7=0;r7<7;r7++){
      float4 h4;
      float x0=xacc[r7][0], x1=xacc[r7][1], x2=xacc[r7][2], x3=xacc[r7][3];
      h4.x = 0.5f*x0*(1.f+erff(x0*0.70710678118654752f));
      h4.y = 0.5f*x1*(1.f+erff(x1*0.70710678118654752f));
      h4.z = 0.5f*x2*(1.f+erff(x2*0.70710678118654752f));
      h4.w = 0.5f*x3*(1.f+erff(x3*0.70710678118654752f));
      *(float4*)&q2h[pg*7+r7][c0] = h4;
    }
  }
  __syncthreads();

  // S4: logits = h @ gw2 + b2
  {
    int e = tid & 31, pq = tid >> 5;
    if (pq < 7){
      float b2v = gb2[e];
      float a0=b2v, a1=b2v, a2=b2v, a3=b2v;
      for (int cc=0;cc<ND;cc+=4){
        float w20 = gw2[(cc+0)*NE + e];
        float w21 = gw2[(cc+1)*NE + e];
        float w22 = gw2[(cc+2)*NE + e];
        float w23 = gw2[(cc+3)*NE + e];
        float4 h0 = *(const float4*)&q2h[pq*4+0][cc];
        float4 h1 = *(const float4*)&q2h[pq*4+1][cc];
        float4 h2 = *(const float4*)&q2h[pq*4+2][cc];
        float4 h3 = *(const float4*)&q2h[pq*4+3][cc];
        a0 += h0.x*w20 + h0.y*w21 + h0.z*w22 + h0.w*w23;
        a1 += h1.x*w20 + h1.y*w21 + h1.z*w22 + h1.w*w23;
        a2 += h2.x*w20 + h2.y*w21 + h2.z*w22 + h2.w*w23;
        a3 += h3.x*w20 + h3.y*w21 + h3.z*w22 + h3.w*w23;
      }
      lg[pq*4+0][e] = a0;
      lg[pq*4+1][e] = a1;
      lg[pq*4+2][e] = a2;
      lg[pq*4+3][e] = a3;
    }
  }
  __syncthreads();

  // S5: top-2 + masked softmax weights
  if (tid < 28){
    float m1 = -1e30f, m2 = -1e30f;
    int e1 = 0, ee2 = 0;
    for (int e3=0;e3<NE;e3++){
      float v = lg[tid][e3];
      if (v > m1){ m2 = m1; ee2 = e1; m1 = v; e1 = e3; }
      else if (v > m2){ m2 = v; ee2 = e3; }
    }
    float z = __expf(m2 - m1);
    float inv = 1.f/(1.f+z);
    sel[tid] = make_float4(__int_as_float(e1), __int_as_float(ee2), inv, z*inv);
  }
  __syncthreads();

  // S6: output mix
  for (int p=0;p<28;p++){
    float4 s = sel[p];
    int e1 = __float_as_int(s.x), ee2 = __float_as_int(s.y);
    float q1v = qe[((size_t)e1*NP + (p0+p))*ND + tid];
    float q2v = qe[((size_t)ee2*NP + (p0+p))*ND + tid];
    out[((size_t)b*NP + (p0+p))*ND + tid] = s.z*q1v + s.w*q2v;
  }
}

extern "C" void kernel_launch(void* const* d_in, const int* in_sizes, int n_in,
                              void* d_out, int out_size, void* d_ws, size_t ws_size,
                              hipStream_t stream)
{
  const float* ctx  = (const float*)d_in[0];
  const float* qe   = (const float*)d_in[1];
  const float* qpos = (const float*)d_in[2];
  const float* lemb = (const float*)d_in[3];
  const float* lat  = (const float*)d_in[4];
  const float* wlq  = (const float*)d_in[5];
  const float* wck  = (const float*)d_in[6];
  const float* wcv  = (const float*)d_in[7];
  const float* wlo  = (const float*)d_in[8];
  const float* wsq  = (const float*)d_in[9];
  const float* wlk  = (const float*)d_in[10];
  const float* wlv  = (const float*)d_in[11];
  const float* wso  = (const float*)d_in[12];
  const float* gw1  = (const float*)d_in[13];
  const float* gb1  = (const float*)d_in[14];
  const float* gw2  = (const float*)d_in[15];
  const float* gb2  = (const float*)d_in[16];
  float* out = (float*)d_out;
  float* ws  = (float*)d_ws;

  pre1<<<512+NP+NL, 256, 0, stream>>>(lat, wlq, wcv, wlo, wso, gw1, gb1, qpos, lemb, wsq, ws);
  pre2<<<256, 256, 0, stream>>>(wck, ws);
  kA  <<<NB*8, 256, 0, stream>>>(ctx, ws);
  kB1 <<<NB, 256, 0, stream>>>(wlk, wlv, ws);
  kB2 <<<NB*6, 256, 0, stream>>>(ws, gw2, gb2, qe, out);
}